// Round 6
// baseline (553.739 us; speedup 1.0000x reference)
//
#include <hip/hip_runtime.h>

#define NN 2048
#define EE 65536
#define BB 8
#define EPSF 1e-5f

typedef _Float16 f16;
typedef __attribute__((ext_vector_type(4))) _Float16 f16x4;
typedef __attribute__((ext_vector_type(8))) _Float16 f16x8;
typedef __attribute__((ext_vector_type(4))) float f32x4;
typedef __attribute__((ext_vector_type(4))) int i32x4;
typedef __attribute__((ext_vector_type(8))) short short8;
typedef __attribute__((ext_vector_type(4))) unsigned short u16x4;

__device__ inline unsigned short f2bf(float f) {
    unsigned u = __float_as_uint(f);
    unsigned r = (u + 0x7fffu + ((u >> 16) & 1u)) >> 16;   // RNE
    return (unsigned short)r;
}

// async global->LDS, 16B per lane; lds dest = wave-uniform base + lane*16
__device__ inline void gload16(const unsigned short* g, unsigned short* l) {
    __builtin_amdgcn_global_load_lds(
        (const __attribute__((address_space(1))) void*)g,
        (__attribute__((address_space(3))) void*)l, 16, 0, 0);
}

// ---------------- graph build ----------------
__global__ void setup_zero(int* __restrict__ counts, int* __restrict__ fillc,
                           float* __restrict__ bnsum, float* __restrict__ bnsq) {
    int i = blockIdx.x * 256 + threadIdx.x;
    if (i < NN) { counts[i] = 0; fillc[i] = 0; }
    if (i < 5 * BB * 1024) { bnsum[i] = 0.f; bnsq[i] = 0.f; }
}

__global__ void count_kernel(const int* __restrict__ ei, int* __restrict__ counts) {
    int e = blockIdx.x * 256 + threadIdx.x;
    if (e < EE + NN) {
        int d = (e < EE) ? ei[EE + e] : (e - EE);
        atomicAdd(&counts[d], 1);
    }
}

__global__ void dinv_kernel(const int* __restrict__ counts, float* __restrict__ dinv) {
    int i = blockIdx.x * 256 + threadIdx.x;
    if (i < NN) dinv[i] = rsqrtf((float)counts[i]);
}

// exclusive scan of counts PADDED UP TO MULTIPLE OF 8 -> row_ptr (aligned CSR rows)
__global__ void scan_kernel(const int* __restrict__ counts, int* __restrict__ row_ptr) {
    __shared__ int sh[256];
    int tid = threadIdx.x;
    int loc[8];
    int run = 0;
#pragma unroll
    for (int i = 0; i < 8; ++i) {
        loc[i] = run;
        run += (counts[tid * 8 + i] + 7) & ~7;
    }
    sh[tid] = run;
    __syncthreads();
    for (int off = 1; off < 256; off <<= 1) {
        int v = (tid >= off) ? sh[tid - off] : 0;
        __syncthreads();
        sh[tid] += v;
        __syncthreads();
    }
    int excl = sh[tid] - run;
#pragma unroll
    for (int i = 0; i < 8; ++i) row_ptr[tid * 8 + i] = excl + loc[i];
    if (tid == 255) row_ptr[NN] = excl + run;
}

// fill real edges (atomic slot) + fill pad slots (col=dst, val=0); disjoint ranges
__global__ void fill_pad(const int* __restrict__ ei, const float* __restrict__ dinv,
                         const int* __restrict__ row_ptr, const int* __restrict__ counts,
                         int* __restrict__ fillc, int* __restrict__ colA, float* __restrict__ valA) {
    int e = blockIdx.x * 256 + threadIdx.x;
    if (e < EE + NN) {
        int s, d;
        if (e < EE) { s = ei[e]; d = ei[EE + e]; }
        else        { s = d = e - EE; }
        int pos = row_ptr[d] + atomicAdd(&fillc[d], 1);
        colA[pos] = s;
        valA[pos] = dinv[s] * dinv[d];
    } else if (e < EE + 2 * NN) {
        int d = e - (EE + NN);
        int beg = row_ptr[d], end = row_ptr[d + 1];
        for (int k = counts[d]; k < end - beg; ++k) {
            colA[beg + k] = d;
            valA[beg + k] = 0.f;
        }
    }
}

__global__ void rowsum_kernel(const int* __restrict__ row_ptr, const float* __restrict__ valA,
                              float* __restrict__ R) {
    int d = blockIdx.x * 256 + threadIdx.x;
    if (d < NN) {
        float s = 0.f;
        for (int j = row_ptr[d]; j < row_ptr[d + 1]; ++j) s += valA[j];
        R[d] = s;
    }
}

// all 5 weight matrices -> one contiguous bf16 buffer (GEMM stays bf16, R3-proven)
#define WO1 16384
#define WO2 (WO1 + 131072)
#define WO3 (WO2 + 524288)
#define WO4 (WO3 + 1048576)
#define WO5 (WO4 + 1048576)
__global__ void conv_all(const float* __restrict__ s0, const float* __restrict__ s1,
                         const float* __restrict__ s2, const float* __restrict__ s3,
                         const float* __restrict__ s4, unsigned short* __restrict__ dst) {
    int i = blockIdx.x * 256 + threadIdx.x;
    if (i >= WO5) return;
    float v;
    if (i < WO1)      v = s0[i];
    else if (i < WO2) v = s1[i - WO1];
    else if (i < WO3) v = s2[i - WO2];
    else if (i < WO4) v = s3[i - WO3];
    else              v = s4[i - WO4];
    dst[i] = f2bf(v);
}

// ---------------- aggregation, layer 1 (f32 input x, F=64) -> bf16 bufA ----------------
__global__ __launch_bounds__(256) void agg_f32(
    const float* __restrict__ Yin, const int* __restrict__ row_ptr,
    const int* __restrict__ colA, const float* __restrict__ valA,
    unsigned short* __restrict__ Aout) {
    constexpr int TPD = 16, DPB = 16, F = 64;
    int b = blockIdx.x & 7;
    int dst = (blockIdx.x >> 3) * DPB + threadIdx.x / TPD;
    int lane = threadIdx.x % TPD;
    const f32x4* Yb = (const f32x4*)(Yin + (size_t)b * NN * F);
    int beg = row_ptr[dst], end = row_ptr[dst + 1];
    f32x4 acc = {0.f, 0.f, 0.f, 0.f};
    for (int j = beg; j < end; j += 8) {
        i32x4 ca = *(const i32x4*)(colA + j);
        i32x4 cb = *(const i32x4*)(colA + j + 4);
        f32x4 va = *(const f32x4*)(valA + j);
        f32x4 vb = *(const f32x4*)(valA + j + 4);
        f32x4 y[8];
#pragma unroll
        for (int e = 0; e < 4; ++e) y[e] = Yb[(size_t)ca[e] * (F / 4) + lane];
#pragma unroll
        for (int e = 0; e < 4; ++e) y[4 + e] = Yb[(size_t)cb[e] * (F / 4) + lane];
#pragma unroll
        for (int e = 0; e < 8; ++e) {
            float ve = (e < 4) ? va[e] : vb[e - 4];
            acc += ve * y[e];
        }
    }
    u16x4 ob = {f2bf(acc[0]), f2bf(acc[1]), f2bf(acc[2]), f2bf(acc[3])};
    *(u16x4*)(Aout + (size_t)b * NN * F + (size_t)dst * F + lane * 4) = ob;
}

// ---------------- aggregation, layers 2..5 (f16 Y, f32 acc, BN affine folded) ----------------
// Aout[b][dst][f] (bf16) = s[b][f] * sum_j val[j]*Y[b][col[j]][f] + t[b][f]*R[dst]
// F/8 threads per dst, 8 f16 feats per thread; (float)f16 * f32 + f32 -> v_fma_mix_f32.
template <int F>
__global__ __launch_bounds__(256) void agg_mix(
    const f16* __restrict__ Yin, const int* __restrict__ row_ptr,
    const int* __restrict__ colA, const float* __restrict__ valA,
    const float* __restrict__ rowsumR, const float* __restrict__ s_arr,
    const float* __restrict__ t_arr, unsigned short* __restrict__ Aout) {
    constexpr int TPD = F / 8;
    constexpr int DPB = 256 / TPD;
    int b = blockIdx.x & 7;
    int dst = (blockIdx.x >> 3) * DPB + threadIdx.x / TPD;
    int lane = threadIdx.x % TPD;
    const f16* Yb = Yin + (size_t)b * NN * F;
    int beg = row_ptr[dst], end = row_ptr[dst + 1];
    float acc[8] = {};
    for (int j = beg; j < end; j += 8) {
        i32x4 ca = *(const i32x4*)(colA + j);
        i32x4 cb = *(const i32x4*)(colA + j + 4);
        f32x4 va = *(const f32x4*)(valA + j);
        f32x4 vb = *(const f32x4*)(valA + j + 4);
        f16x8 y[8];
#pragma unroll
        for (int e = 0; e < 4; ++e) y[e] = *(const f16x8*)(Yb + (size_t)ca[e] * F + lane * 8);
#pragma unroll
        for (int e = 0; e < 4; ++e) y[4 + e] = *(const f16x8*)(Yb + (size_t)cb[e] * F + lane * 8);
#pragma unroll
        for (int e = 0; e < 8; ++e) {
            float ve = (e < 4) ? va[e] : vb[e - 4];
#pragma unroll
            for (int k = 0; k < 8; ++k)
                acc[k] = __builtin_fmaf((float)y[e][k], ve, acc[k]);  // v_fma_mix_f32
        }
    }
    float R = rowsumR[dst];
    const float* sb = s_arr + b * F + lane * 8;
    const float* tb = t_arr + b * F + lane * 8;
    unsigned short ob[8];
#pragma unroll
    for (int k = 0; k < 8; ++k)
        ob[k] = f2bf(sb[k] * acc[k] + tb[k] * R);
    *(short8*)(Aout + (size_t)b * NN * F + (size_t)dst * F + lane * 8) = *(short8*)ob;
}

// ---------------- bf16 MFMA GEMM: Y(f16) = lrelu(A @ W^T + bias), BN stats fused ----------------
__global__ __launch_bounds__(256) void gemm_bias_lrelu(
    const unsigned short* __restrict__ A, const unsigned short* __restrict__ W,
    const float* __restrict__ bias, f16* __restrict__ Y,
    float* __restrict__ bnsum, float* __restrict__ bnsq, int K, int F) {
    __shared__ unsigned short lds_a[128 * 32];
    __shared__ unsigned short lds_b[128 * 32];
    const int tid = threadIdx.x;
    const int row0 = blockIdx.x * 128;
    const int col0 = blockIdx.y * 128;
    const int b = row0 >> 11;
    const int wave = tid >> 6;
    const int lane = tid & 63;
    const int wr = (wave >> 1) * 64;
    const int wc = (wave & 1) * 64;
    const int lrow = lane & 15;
    const int q = lane >> 4;
    const int lr = lane >> 2;
    const int lk = (lane & 3) * 8;

    f32x4 acc[4][4] = {};

    for (int k0 = 0; k0 < K; k0 += 32) {
#pragma unroll
        for (int t = 0; t < 2; ++t) {
            int r = wave * 32 + t * 16;
            gload16(A + (size_t)(row0 + r + lr) * K + k0 + lk, lds_a + r * 32);
            gload16(W + (size_t)(col0 + r + lr) * K + k0 + lk, lds_b + r * 32);
        }
        __syncthreads();
        short8 af[4], bf[4];
#pragma unroll
        for (int mt = 0; mt < 4; ++mt)
            af[mt] = *(const short8*)(lds_a + (wr + mt * 16 + lrow) * 32 + q * 8);
#pragma unroll
        for (int nt = 0; nt < 4; ++nt)
            bf[nt] = *(const short8*)(lds_b + (wc + nt * 16 + lrow) * 32 + q * 8);
#pragma unroll
        for (int mt = 0; mt < 4; ++mt)
#pragma unroll
            for (int nt = 0; nt < 4; ++nt)
                acc[mt][nt] = __builtin_amdgcn_mfma_f32_16x16x32_bf16(af[mt], bf[nt], acc[mt][nt], 0, 0, 0);
        __syncthreads();
    }
#pragma unroll
    for (int nt = 0; nt < 4; ++nt) {
        int col = col0 + wc + nt * 16 + lrow;
        float bv = bias[col];
        float s = 0.f, s2 = 0.f;
#pragma unroll
        for (int mt = 0; mt < 4; ++mt) {
#pragma unroll
            for (int reg = 0; reg < 4; ++reg) {
                int row = row0 + wr + mt * 16 + q * 4 + reg;
                float v = acc[mt][nt][reg] + bv;
                v = (v > 0.f) ? v : 0.01f * v;
                s += v;
                s2 += v * v;
                Y[(size_t)row * F + col] = (f16)v;
            }
        }
        s += __shfl_xor(s, 16);
        s2 += __shfl_xor(s2, 16);
        s += __shfl_xor(s, 32);
        s2 += __shfl_xor(s2, 32);
        if (q == 0) {
            atomicAdd(&bnsum[b * F + col], s);
            atomicAdd(&bnsq[b * F + col], s2);
        }
    }
}

__global__ void bn_finalize(const float* __restrict__ sum, const float* __restrict__ sq,
                            const float* __restrict__ g, const float* __restrict__ be,
                            float* __restrict__ s_arr, float* __restrict__ t_arr, int F) {
    int i = blockIdx.x * 256 + threadIdx.x;
    if (i >= BB * F) return;
    int c = i % F;
    float mu = sum[i] * (1.f / NN);
    float var = sq[i] * (1.f / NN) - mu * mu;
    float rs = rsqrtf(var + EPSF);
    float sc = g[c] * rs;
    s_arr[i] = sc;
    t_arr[i] = be[c] - mu * sc;
}

// ---------------- final layernorm (reads f16 Y, applies layer-5 BN) ----------------
__global__ __launch_bounds__(256) void final_ln(const f16* __restrict__ Y,
                                                const float* __restrict__ s_arr, const float* __restrict__ t_arr,
                                                const float* __restrict__ lng, const float* __restrict__ lnb,
                                                float* __restrict__ out) {
    int bn = blockIdx.x;
    int b = bn >> 11;
    int tid = threadIdx.x;
    f16x4 hr = ((const f16x4*)(Y + (size_t)bn * 1024))[tid];
    f32x4 h = {(float)hr[0], (float)hr[1], (float)hr[2], (float)hr[3]};
    f32x4 sv = ((const f32x4*)(s_arr + b * 1024))[tid];
    f32x4 tv = ((const f32x4*)(t_arr + b * 1024))[tid];
    h = sv * h + tv;
    float s = h[0] + h[1] + h[2] + h[3];
    float s2 = h[0] * h[0] + h[1] * h[1] + h[2] * h[2] + h[3] * h[3];
#pragma unroll
    for (int off = 32; off; off >>= 1) {
        s += __shfl_down(s, off);
        s2 += __shfl_down(s2, off);
    }
    __shared__ float ssum[4], ssq[4];
    int wv = tid >> 6, ln = tid & 63;
    if (ln == 0) { ssum[wv] = s; ssq[wv] = s2; }
    __syncthreads();
    if (tid == 0) {
        float S = ssum[0] + ssum[1] + ssum[2] + ssum[3];
        float Q = ssq[0] + ssq[1] + ssq[2] + ssq[3];
        float mu = S * (1.f / 1024.f);
        float var = Q * (1.f / 1024.f) - mu * mu;
        ssum[0] = mu;
        ssq[0] = rsqrtf(var + EPSF);
    }
    __syncthreads();
    float mu = ssum[0], rs = ssq[0];
    f32x4 gv = ((const f32x4*)lng)[tid];
    f32x4 bv = ((const f32x4*)lnb)[tid];
    f32x4 o = (h - mu) * rs * gv + bv;
    ((f32x4*)(out + (size_t)bn * 1024))[tid] = o;
}

// ---------------- host ----------------
extern "C" void kernel_launch(void* const* d_in, const int* in_sizes, int n_in,
                              void* d_out, int out_size, void* d_ws, size_t ws_size,
                              hipStream_t stream) {
    const float* w[5]    = {(const float*)d_in[0], (const float*)d_in[4], (const float*)d_in[8],
                            (const float*)d_in[12], (const float*)d_in[16]};
    const float* bias[5] = {(const float*)d_in[1], (const float*)d_in[5], (const float*)d_in[9],
                            (const float*)d_in[13], (const float*)d_in[17]};
    const float* gam[5]  = {(const float*)d_in[2], (const float*)d_in[6], (const float*)d_in[10],
                            (const float*)d_in[14], (const float*)d_in[18]};
    const float* bet[5]  = {(const float*)d_in[3], (const float*)d_in[7], (const float*)d_in[11],
                            (const float*)d_in[15], (const float*)d_in[19]};
    const float* ln_g = (const float*)d_in[20];
    const float* ln_b = (const float*)d_in[21];
    const float* x    = (const float*)d_in[22];
    const int* ei     = (const int*)d_in[23];

    char* p = (char*)d_ws;
    auto alloc = [&](size_t bytes) {
        char* r = p;
        p += (bytes + 255) & ~(size_t)255;
        return r;
    };
    const int MAXE = EE + 8 * NN;  // rows padded to multiple of 8
    float* dinv    = (float*)alloc(NN * 4);
    float* rowsumR = (float*)alloc(NN * 4);
    int* row_ptr   = (int*)alloc((NN + 1) * 4);
    int* counts    = (int*)alloc(NN * 4);
    int* fillc     = (int*)alloc(NN * 4);
    int* colA      = (int*)alloc((size_t)MAXE * 4);
    float* valA    = (float*)alloc((size_t)MAXE * 4);
    float* bnsum   = (float*)alloc((size_t)5 * BB * 1024 * 4);
    float* bnsq    = (float*)alloc((size_t)5 * BB * 1024 * 4);
    float* s_arr   = (float*)alloc((size_t)BB * 1024 * 4);
    float* t_arr   = (float*)alloc((size_t)BB * 1024 * 4);
    unsigned short* wbf = (unsigned short*)alloc((size_t)WO5 * 2);
    unsigned short* bufA = (unsigned short*)alloc((size_t)BB * NN * 1024 * 2);
    f16* bufY = (f16*)alloc((size_t)BB * NN * 1024 * 2);
    const int wofs[5] = {0, WO1, WO2, WO3, WO4};

    // graph build (once per call; padded CSR shared across batch & layers)
    setup_zero<<<(5 * BB * 1024 + 255) / 256, 256, 0, stream>>>(counts, fillc, bnsum, bnsq);
    count_kernel<<<(EE + NN + 255) / 256, 256, 0, stream>>>(ei, counts);
    dinv_kernel<<<(NN + 255) / 256, 256, 0, stream>>>(counts, dinv);
    scan_kernel<<<1, 256, 0, stream>>>(counts, row_ptr);
    fill_pad<<<(EE + 2 * NN + 255) / 256, 256, 0, stream>>>(ei, dinv, row_ptr, counts, fillc, colA, valA);
    rowsum_kernel<<<(NN + 255) / 256, 256, 0, stream>>>(row_ptr, valA, rowsumR);
    conv_all<<<(WO5 + 255) / 256, 256, 0, stream>>>(w[0], w[1], w[2], w[3], w[4], wbf);

    const int Kin[5]  = {64, 256, 512, 1024, 1024};
    const int Fout[5] = {256, 512, 1024, 1024, 1024};
    for (int l = 0; l < 5; ++l) {
        int K = Kin[l], F = Fout[l];
        if (l == 0) {
            agg_f32<<<(NN / 16) * 8, 256, 0, stream>>>(x, row_ptr, colA, valA, bufA);
        } else {
            switch (K) {
                case 256:
                    agg_mix<256><<<(NN / 8) * 8, 256, 0, stream>>>(bufY, row_ptr, colA, valA, rowsumR, s_arr, t_arr, bufA);
                    break;
                case 512:
                    agg_mix<512><<<(NN / 4) * 8, 256, 0, stream>>>(bufY, row_ptr, colA, valA, rowsumR, s_arr, t_arr, bufA);
                    break;
                default:
                    agg_mix<1024><<<(NN / 2) * 8, 256, 0, stream>>>(bufY, row_ptr, colA, valA, rowsumR, s_arr, t_arr, bufA);
                    break;
            }
        }
        gemm_bias_lrelu<<<dim3(BB * NN / 128, F / 128), 256, 0, stream>>>(
            bufA, wbf + wofs[l], bias[l], bufY, bnsum + l * BB * 1024, bnsq + l * BB * 1024, K, F);
        bn_finalize<<<(BB * F + 255) / 256, 256, 0, stream>>>(
            bnsum + l * BB * 1024, bnsq + l * BB * 1024, gam[l], bet[l], s_arr, t_arr, F);
    }
    final_ln<<<BB * NN, 256, 0, stream>>>(bufY, s_arr, t_arr, ln_g, ln_b, (float*)d_out);
}